// Round 9
// baseline (236.064 us; speedup 1.0000x reference)
//
#include <hip/hip_runtime.h>
#include <math.h>

#define NN 4096
#define DD 512
#define F1 64
#define F2 32
#define F3 16
#define NH 4
#define ALPHA 0.2f
#define CAP 160   // max degree; Binomial(4096,0.01) mean 41, sigma 6.4 -> P(>160)~0
#define KS 8      // K-split factor for the big GEMM (512 gemm blocks, K=64 each)

__device__ __forceinline__ float lrelu(float e) { return (e >= 0.f) ? e : ALPHA * e; }

// ---------------------------------------------------------------------------
// Kernel 0 (merged front): blocks [0,512) = x @ Wcat K-split SGEMM (8x8 reg
// tiles, named-float4 accumulators, R8-verified); blocks [512,4608) = CSR
// build (one adj row each). The two phases touch disjoint data and different
// pipes (gemm: VALU/LDS; csr: HBM), so one launch runs them CONCURRENTLY:
// phase-1 time ~= max(csr, gemm) instead of sum, and one launch gap is gone.
// gemm blocks are dispatched FIRST so the long-lived blocks start early.
// ---------------------------------------------------------------------------
#define FMA8(C0, C1, AV) { float av_ = (AV); \
  C0.x = fmaf(av_, bc0.x, C0.x); \
  C0.y = fmaf(av_, bc0.y, C0.y); \
  C0.z = fmaf(av_, bc0.z, C0.z); \
  C0.w = fmaf(av_, bc0.w, C0.w); \
  C1.x = fmaf(av_, bc1.x, C1.x); \
  C1.y = fmaf(av_, bc1.y, C1.y); \
  C1.z = fmaf(av_, bc1.z, C1.z); \
  C1.w = fmaf(av_, bc1.w, C1.w); }

#define STORE_ROW(C0, C1, ROWEXPR) { \
  int row_ = (ROWEXPR); \
  float* p_ = dst + (size_t)row_ * (NH * F1); \
  *(float4*)&p_[cg * 4] = C0; \
  *(float4*)&p_[cg * 4 + 64] = C1; }

__global__ __launch_bounds__(256) void k_front(
    const float* __restrict__ x, const float* __restrict__ W_heads,
    const float* __restrict__ adj, float* __restrict__ part,
    int* __restrict__ colidx, int* __restrict__ deg) {
  __shared__ float As[32][128];   // gemm A tile [kk][row] transposed, 16 KB
  __shared__ float Bs[32][128];   // gemm B tile [kk][col], 16 KB
  __shared__ int cnt;             // csr counter
  int tid = threadIdx.x;

  if (blockIdx.x < 512) {
    // ---------------- GEMM path: g = kq*64 + nh*32 + mt ----------------
    int g = blockIdx.x;
    int mt = g & 31;                // M-tile 0..31
    int nh = (g >> 5) & 1;          // head pair 0..1
    int kq = g >> 6;                // K-slice 0..7
    int r0 = mt * 128;
    int kb = kq * 64;               // K range [kb, kb+64), 2 chunks of 32

    int arow = tid & 127, ahalf = tid >> 7;   // A staging: row, k-half(16)
    int bk = tid >> 5, bf = tid & 31;         // B staging: k-row base, col quad
    int rg = tid >> 4, cg = tid & 15;         // compute: rows rg*4(+64), cols cg*4(+64)

    const float* xa = x + (size_t)(r0 + arow) * DD + kb + ahalf * 16;
    int h = nh * 2 + (bf >> 4);
    const float* wsrc = W_heads + (size_t)h * DD * F1 + ((bf * 4) & 63);

    // prefetch chunk 0 into NAMED registers
    float4 pa0 = *(const float4*)(xa);
    float4 pa1 = *(const float4*)(xa + 4);
    float4 pa2 = *(const float4*)(xa + 8);
    float4 pa3 = *(const float4*)(xa + 12);
    float4 pb0 = *(const float4*)(wsrc + (size_t)(kb + bk) * F1);
    float4 pb1 = *(const float4*)(wsrc + (size_t)(kb + bk + 8) * F1);
    float4 pb2 = *(const float4*)(wsrc + (size_t)(kb + bk + 16) * F1);
    float4 pb3 = *(const float4*)(wsrc + (size_t)(kb + bk + 24) * F1);

    float4 c00 = {0,0,0,0}, c01 = {0,0,0,0};
    float4 c10 = {0,0,0,0}, c11 = {0,0,0,0};
    float4 c20 = {0,0,0,0}, c21 = {0,0,0,0};
    float4 c30 = {0,0,0,0}, c31 = {0,0,0,0};
    float4 c40 = {0,0,0,0}, c41 = {0,0,0,0};
    float4 c50 = {0,0,0,0}, c51 = {0,0,0,0};
    float4 c60 = {0,0,0,0}, c61 = {0,0,0,0};
    float4 c70 = {0,0,0,0}, c71 = {0,0,0,0};

#pragma unroll
    for (int c = 0; c < 2; ++c) {
      {
        int kk0 = ahalf * 16;
        As[kk0 + 0][arow] = pa0.x; As[kk0 + 1][arow] = pa0.y;
        As[kk0 + 2][arow] = pa0.z; As[kk0 + 3][arow] = pa0.w;
        As[kk0 + 4][arow] = pa1.x; As[kk0 + 5][arow] = pa1.y;
        As[kk0 + 6][arow] = pa1.z; As[kk0 + 7][arow] = pa1.w;
        As[kk0 + 8][arow] = pa2.x; As[kk0 + 9][arow] = pa2.y;
        As[kk0 + 10][arow] = pa2.z; As[kk0 + 11][arow] = pa2.w;
        As[kk0 + 12][arow] = pa3.x; As[kk0 + 13][arow] = pa3.y;
        As[kk0 + 14][arow] = pa3.z; As[kk0 + 15][arow] = pa3.w;
        *(float4*)&Bs[bk][bf * 4] = pb0;
        *(float4*)&Bs[bk + 8][bf * 4] = pb1;
        *(float4*)&Bs[bk + 16][bf * 4] = pb2;
        *(float4*)&Bs[bk + 24][bf * 4] = pb3;
      }
      __syncthreads();
      if (c == 0) {   // issue chunk-1 loads; latency hides under chunk-0 FMAs
        pa0 = *(const float4*)(xa + 32);
        pa1 = *(const float4*)(xa + 36);
        pa2 = *(const float4*)(xa + 40);
        pa3 = *(const float4*)(xa + 44);
        pb0 = *(const float4*)(wsrc + (size_t)(kb + 32 + bk) * F1);
        pb1 = *(const float4*)(wsrc + (size_t)(kb + 32 + bk + 8) * F1);
        pb2 = *(const float4*)(wsrc + (size_t)(kb + 32 + bk + 16) * F1);
        pb3 = *(const float4*)(wsrc + (size_t)(kb + 32 + bk + 24) * F1);
      }
#pragma unroll
      for (int kk = 0; kk < 32; ++kk) {
        float4 ar0 = *(const float4*)&As[kk][rg * 4];
        float4 ar1 = *(const float4*)&As[kk][rg * 4 + 64];
        float4 bc0 = *(const float4*)&Bs[kk][cg * 4];
        float4 bc1 = *(const float4*)&Bs[kk][cg * 4 + 64];
        FMA8(c00, c01, ar0.x)
        FMA8(c10, c11, ar0.y)
        FMA8(c20, c21, ar0.z)
        FMA8(c30, c31, ar0.w)
        FMA8(c40, c41, ar1.x)
        FMA8(c50, c51, ar1.y)
        FMA8(c60, c61, ar1.z)
        FMA8(c70, c71, ar1.w)
      }
      if (c == 0) __syncthreads();
    }

    float* dst = part + (size_t)kq * NN * (NH * F1) + nh * 128;
    STORE_ROW(c00, c01, r0 + rg * 4 + 0)
    STORE_ROW(c10, c11, r0 + rg * 4 + 1)
    STORE_ROW(c20, c21, r0 + rg * 4 + 2)
    STORE_ROW(c30, c31, r0 + rg * 4 + 3)
    STORE_ROW(c40, c41, r0 + 64 + rg * 4 + 0)
    STORE_ROW(c50, c51, r0 + 64 + rg * 4 + 1)
    STORE_ROW(c60, c61, r0 + 64 + rg * 4 + 2)
    STORE_ROW(c70, c71, r0 + 64 + rg * 4 + 3)
  } else {
    // ---------------- CSR path: row i ----------------
    int i = blockIdx.x - 512;
    if (tid == 0) cnt = 0;
    __syncthreads();
    const float4* arow = (const float4*)(adj + (size_t)i * NN);
    for (int t = tid; t < NN / 4; t += 256) {
      float4 v = arow[t];
      int base = t * 4;
      if (v.x != 0.f) { int p = atomicAdd(&cnt, 1); if (p < CAP) colidx[(size_t)i * CAP + p] = base; }
      if (v.y != 0.f) { int p = atomicAdd(&cnt, 1); if (p < CAP) colidx[(size_t)i * CAP + p] = base + 1; }
      if (v.z != 0.f) { int p = atomicAdd(&cnt, 1); if (p < CAP) colidx[(size_t)i * CAP + p] = base + 2; }
      if (v.w != 0.f) { int p = atomicAdd(&cnt, 1); if (p < CAP) colidx[(size_t)i * CAP + p] = base + 3; }
    }
    __syncthreads();
    if (tid == 0) deg[i] = cnt < CAP ? cnt : CAP;
  }
}

// ---------------------------------------------------------------------------
// Kernel 1b: combine KS partials -> Whcat (float4), fused s1/s2 reductions.
// ---------------------------------------------------------------------------
__global__ void k_wh_comb(const float* __restrict__ part,
                          const float* __restrict__ a_heads,
                          float* __restrict__ Whcat,
                          float* __restrict__ s1, float* __restrict__ s2) {
  int tid = threadIdx.x;
  int r0 = blockIdx.x * 8;
  int rb = tid >> 6;        // 0..3
  int c4 = tid & 63;        // quad col 0..63 (covers 256 cols)
  int h = c4 >> 4;          // 0..3: all 4 heads
  int f0 = (c4 & 15) * 4;
  float4 a1 = *(const float4*)&a_heads[h * 2 * F1 + f0];
  float4 a2 = *(const float4*)&a_heads[h * 2 * F1 + F1 + f0];
  const size_t stride = (size_t)NN * (NH * F1);
#pragma unroll
  for (int rr = 0; rr < 2; ++rr) {
    int row = r0 + rb * 2 + rr;
    size_t off = (size_t)row * (NH * F1) + c4 * 4;
    float4 v = *(const float4*)&part[off];
#pragma unroll
    for (int s = 1; s < KS; ++s) {
      float4 p = *(const float4*)&part[off + (size_t)s * stride];
      v.x += p.x; v.y += p.y; v.z += p.z; v.w += p.w;
    }
    *(float4*)&Whcat[off] = v;
    float v1 = v.x * a1.x + v.y * a1.y + v.z * a1.z + v.w * a1.w;
    float v2 = v.x * a2.x + v.y * a2.y + v.z * a2.z + v.w * a2.w;
#pragma unroll
    for (int o = 8; o > 0; o >>= 1) {
      v1 += __shfl_down(v1, o, 16);
      v2 += __shfl_down(v2, o, 16);
    }
    if ((tid & 15) == 0) {
      s1[h * NN + row] = v1;
      s2[h * NN + row] = v2;
    }
  }
}

// ---------------------------------------------------------------------------
// Kernel 2: multi-head GAT aggregation. Block per row; wave h = head h.
// ---------------------------------------------------------------------------
__global__ void k_gat_heads(const int* __restrict__ colidx, const int* __restrict__ deg,
                            const float* __restrict__ Whcat,
                            const float* __restrict__ s1, const float* __restrict__ s2,
                            float* __restrict__ cat) {
  __shared__ int idx[CAP];
  __shared__ float wsh[NH][CAP];
  int i = blockIdx.x, tid = threadIdx.x;
  int c = deg[i];
  for (int t = tid; t < c; t += 256) idx[t] = colidx[(size_t)i * CAP + t];
  __syncthreads();
  int h = tid >> 6;
  int f = tid & 63;
  const float* s2h = s2 + h * NN;
  float s1v = s1[h * NN + i];
  float M = -INFINITY;
  for (int k = f; k < c; k += 64) {
    float v = s2h[idx[k]];
    wsh[h][k] = v;
    M = fmaxf(M, v);
  }
#pragma unroll
  for (int off = 32; off > 0; off >>= 1) M = fmaxf(M, __shfl_down(M, off, 64));
  M = __shfl(M, 0, 64);
  float m = lrelu(s1v + M);
  float lsum = 0.f;
  for (int k = f; k < c; k += 64) {
    float w = __expf(lrelu(s1v + wsh[h][k]) - m);
    wsh[h][k] = w;
    lsum += w;
  }
#pragma unroll
  for (int off = 32; off > 0; off >>= 1) lsum += __shfl_down(lsum, off, 64);
  float linv = 1.f / __shfl(lsum, 0, 64);
  __syncthreads();
  const float* base = Whcat + h * 64 + f;
  float a0 = 0.f, a1 = 0.f, a2 = 0.f, a3 = 0.f;
  int k = 0;
  for (; k + 4 <= c; k += 4) {
    int j0 = idx[k], j1 = idx[k + 1], j2 = idx[k + 2], j3 = idx[k + 3];
    a0 = fmaf(wsh[h][k],     base[(size_t)j0 * 256], a0);
    a1 = fmaf(wsh[h][k + 1], base[(size_t)j1 * 256], a1);
    a2 = fmaf(wsh[h][k + 2], base[(size_t)j2 * 256], a2);
    a3 = fmaf(wsh[h][k + 3], base[(size_t)j3 * 256], a3);
  }
  for (; k < c; ++k) a0 = fmaf(wsh[h][k], base[(size_t)idx[k] * 256], a0);
  float o = (a0 + a1 + a2 + a3) * linv;
  cat[(size_t)i * (NH * F1) + tid] = (o > 0.f) ? o : expm1f(o);
}

// ---------------------------------------------------------------------------
// Kernel 3: Wh2 = cat @ W_att  [NN,256]x[256,64], plus s1b/s2b reductions
// ---------------------------------------------------------------------------
__global__ void k_wh2(const float* __restrict__ cat,
                      const float* __restrict__ W_att,
                      const float* __restrict__ a_att,
                      float* __restrict__ Wh2,
                      float* __restrict__ s1b, float* __restrict__ s2b) {
  const int ROWS = 8;
  __shared__ float cs[ROWS][NH * F1];
  int tid = threadIdx.x;
  int r0 = blockIdx.x * ROWS;
  const float4* csrc = (const float4*)(cat + (size_t)r0 * 256);
  for (int t = tid; t < ROWS * 256 / 4; t += 256) ((float4*)cs)[t] = csrc[t];
  __syncthreads();
  int g = tid >> 6;
  int f = tid & 63;
  float a1 = a_att[f], a2 = a_att[64 + f];
  const float* W = W_att + f;
#pragma unroll
  for (int rr = 0; rr < 2; ++rr) {
    int r = g * 2 + rr;
    float acc = 0.f;
    for (int k = 0; k < 256; k += 4) {
      float4 cv = *(const float4*)&cs[r][k];
      acc = fmaf(cv.x, W[(k + 0) * 64], acc);
      acc = fmaf(cv.y, W[(k + 1) * 64], acc);
      acc = fmaf(cv.z, W[(k + 2) * 64], acc);
      acc = fmaf(cv.w, W[(k + 3) * 64], acc);
    }
    Wh2[(size_t)(r0 + r) * 64 + f] = acc;
    float v1 = acc * a1, v2 = acc * a2;
#pragma unroll
    for (int off = 32; off > 0; off >>= 1) {
      v1 += __shfl_down(v1, off, 64);
      v2 += __shfl_down(v2, off, 64);
    }
    if (f == 0) { s1b[r0 + r] = v1; s2b[r0 + r] = v2; }
  }
}

// ---------------------------------------------------------------------------
// Kernel 4: single-head GAT + fused t1 = gc @ W1. 4 rows/block, wave per row.
// ---------------------------------------------------------------------------
__global__ void k_gat2t1(const int* __restrict__ colidx, const int* __restrict__ deg,
                         const float* __restrict__ Wh2,
                         const float* __restrict__ s1b, const float* __restrict__ s2b,
                         const float* __restrict__ W1, float* __restrict__ t1) {
  __shared__ int idx4[4][CAP];
  __shared__ float wsh4[4][CAP];
  __shared__ float grow[4][64];
  __shared__ float W1s[F1 * F2];  // 8 KB
  int tid = threadIdx.x;
  int w = tid >> 6, f = tid & 63;
  int i = blockIdx.x * 4 + w;
  int c = deg[i];
  for (int t = tid; t < F1 * F2; t += 256) W1s[t] = W1[t];
  for (int k = f; k < c; k += 64) idx4[w][k] = colidx[(size_t)i * CAP + k];
  __syncthreads();
  float s1v = s1b[i];
  float M = -INFINITY;
  for (int k = f; k < c; k += 64) {
    float v = s2b[idx4[w][k]];
    wsh4[w][k] = v;
    M = fmaxf(M, v);
  }
#pragma unroll
  for (int off = 32; off > 0; off >>= 1) M = fmaxf(M, __shfl_down(M, off, 64));
  M = __shfl(M, 0, 64);
  float m = lrelu(s1v + M);
  float lsum = 0.f;
  for (int k = f; k < c; k += 64) {
    float wv = __expf(lrelu(s1v + wsh4[w][k]) - m);
    wsh4[w][k] = wv;
    lsum += wv;
  }
#pragma unroll
  for (int off = 32; off > 0; off >>= 1) lsum += __shfl_down(lsum, off, 64);
  float linv = 1.f / __shfl(lsum, 0, 64);
  __syncthreads();
  const float* base = Wh2 + f;
  float a0 = 0.f, a1 = 0.f, a2 = 0.f, a3 = 0.f;
  int k = 0;
  for (; k + 4 <= c; k += 4) {
    int j0 = idx4[w][k], j1 = idx4[w][k + 1], j2 = idx4[w][k + 2], j3 = idx4[w][k + 3];
    a0 = fmaf(wsh4[w][k],     base[(size_t)j0 * 64], a0);
    a1 = fmaf(wsh4[w][k + 1], base[(size_t)j1 * 64], a1);
    a2 = fmaf(wsh4[w][k + 2], base[(size_t)j2 * 64], a2);
    a3 = fmaf(wsh4[w][k + 3], base[(size_t)j3 * 64], a3);
  }
  for (; k < c; ++k) a0 = fmaf(wsh4[w][k], base[(size_t)idx4[w][k] * 64], a0);
  float o = (a0 + a1 + a2 + a3) * linv;
  grow[w][f] = (o > 0.f) ? o : expm1f(o);
  __syncthreads();
  if (f < F2) {
    float acc = 0.f;
#pragma unroll 8
    for (int kk = 0; kk < F1; ++kk) acc = fmaf(grow[w][kk], W1s[kk * F2 + f], acc);
    t1[(size_t)i * F2 + f] = acc;
  }
}

// ---------------------------------------------------------------------------
// Kernel 5: h1 = relu(adj @ t1) fused with t23 = h1 @ [W2|W3].
// ---------------------------------------------------------------------------
__global__ void k_gcn1t23(const int* __restrict__ colidx, const int* __restrict__ deg,
                          const float* __restrict__ t1,
                          const float* __restrict__ W2, const float* __restrict__ W3,
                          float* __restrict__ t23) {
  __shared__ int idx4[4][CAP];
  __shared__ float hrow[4][F2];
  __shared__ float Wc[F2 * 32];  // [k][g]: g<16 -> W2, g>=16 -> W3
  int tid = threadIdx.x;
  int w = tid >> 6, lane = tid & 63;
  int nb = lane >> 5, g = lane & 31;
  int i = blockIdx.x * 4 + w;
  int c = deg[i];
  for (int t = tid; t < F2 * 32; t += 256) {
    int kk = t >> 5, gg = t & 31;
    Wc[t] = (gg < 16) ? W2[kk * 16 + gg] : W3[kk * 16 + (gg - 16)];
  }
  for (int k = lane; k < c; k += 64) idx4[w][k] = colidx[(size_t)i * CAP + k];
  __syncthreads();
  float a0 = 0.f, a1 = 0.f;
  int k = nb;
  for (; k + 2 < c; k += 4) {
    a0 += t1[(size_t)idx4[w][k] * F2 + g];
    a1 += t1[(size_t)idx4[w][k + 2] * F2 + g];
  }
  for (; k < c; k += 2) a0 += t1[(size_t)idx4[w][k] * F2 + g];
  float tot = a0 + a1;
  tot += __shfl_xor(tot, 32, 64);
  float h1v = fmaxf(tot, 0.f);
  if (nb == 0) hrow[w][g] = h1v;
  __syncthreads();
  if (lane < 32) {
    float acc = 0.f;
#pragma unroll 8
    for (int kk = 0; kk < F2; ++kk) acc = fmaf(hrow[w][kk], Wc[kk * 32 + lane], acc);
    t23[(size_t)i * 32 + lane] = acc;
  }
}

// ---------------------------------------------------------------------------
// Kernel 6: mu/logvar = adj @ t23 ; z = eps*exp(logvar)+mu. Wave per row.
// ---------------------------------------------------------------------------
__global__ void k_gcn2(const int* __restrict__ colidx, const int* __restrict__ deg,
                       const float* __restrict__ t23, const float* __restrict__ eps,
                       float* __restrict__ mu_out, float* __restrict__ lv_out,
                       float* __restrict__ z) {
  __shared__ int idx4[4][CAP];
  int tid = threadIdx.x;
  int w = tid >> 6, lane = tid & 63;
  int nb = lane >> 5, g = lane & 31;
  int i = blockIdx.x * 4 + w;
  int c = deg[i];
  for (int k = lane; k < c; k += 64) idx4[w][k] = colidx[(size_t)i * CAP + k];
  __syncthreads();
  float a0 = 0.f, a1 = 0.f;
  int k = nb;
  for (; k + 2 < c; k += 4) {
    a0 += t23[(size_t)idx4[w][k] * 32 + g];
    a1 += t23[(size_t)idx4[w][k + 2] * 32 + g];
  }
  for (; k < c; k += 2) a0 += t23[(size_t)idx4[w][k] * 32 + g];
  float tot = a0 + a1;
  tot += __shfl_xor(tot, 32, 64);
  float lvv = __shfl(tot, (lane & 31) + 16, 64);  // valid for g<16
  if (lane < 16) {
    mu_out[(size_t)i * 16 + g] = tot;
    z[(size_t)i * 16 + g] = eps[(size_t)i * 16 + g] * expf(lvv) + tot;
  } else if (lane < 32) {
    lv_out[(size_t)i * 16 + (g - 16)] = tot;
  }
}

// ---------------------------------------------------------------------------
// Kernel 7: adj_rec = z @ z^T. 64x64 tiles, rank-16, float4 stores.
// ---------------------------------------------------------------------------
__global__ void k_zzt(const float* __restrict__ z, float* __restrict__ out) {
  __shared__ float zr[64][17];
  __shared__ float zc[64][17];
  int bj = blockIdx.x, bi = blockIdx.y;
  int tid = threadIdx.x;
  for (int t = tid; t < 64 * 16; t += 256) {
    int r = t >> 4, kk = t & 15;
    zr[r][kk] = z[(size_t)(bi * 64 + r) * 16 + kk];
    zc[r][kk] = z[(size_t)(bj * 64 + r) * 16 + kk];
  }
  __syncthreads();
  int rg = tid >> 4;
  int cg = tid & 15;
  float acc[4][4] = {};
  for (int kk = 0; kk < 16; ++kk) {
    float av[4], bv[4];
#pragma unroll
    for (int t = 0; t < 4; ++t) av[t] = zr[rg * 4 + t][kk];
#pragma unroll
    for (int t = 0; t < 4; ++t) bv[t] = zc[cg * 4 + t][kk];
#pragma unroll
    for (int r = 0; r < 4; ++r)
#pragma unroll
      for (int cc = 0; cc < 4; ++cc) acc[r][cc] = fmaf(av[r], bv[cc], acc[r][cc]);
  }
#pragma unroll
  for (int r = 0; r < 4; ++r) {
    float4 v = make_float4(acc[r][0], acc[r][1], acc[r][2], acc[r][3]);
    *(float4*)&out[(size_t)(bi * 64 + rg * 4 + r) * NN + bj * 64 + cg * 4] = v;
  }
}

extern "C" void kernel_launch(void* const* d_in, const int* in_sizes, int n_in,
                              void* d_out, int out_size, void* d_ws, size_t ws_size,
                              hipStream_t stream) {
  const float* x       = (const float*)d_in[0];
  const float* adj     = (const float*)d_in[1];
  const float* W_heads = (const float*)d_in[2];
  const float* a_heads = (const float*)d_in[3];
  const float* W_att   = (const float*)d_in[4];
  const float* a_att   = (const float*)d_in[5];
  const float* W1      = (const float*)d_in[6];
  const float* W2      = (const float*)d_in[7];
  const float* W3      = (const float*)d_in[8];
  const float* eps     = (const float*)d_in[9];

  float* out = (float*)d_out;
  float* adj_rec = out;
  float* mu_out  = out + (size_t)NN * NN;
  float* lv_out  = mu_out + (size_t)NN * F3;

  float* ws = (float*)d_ws;
  float* Whcat = ws;               ws += (size_t)NN * NH * F1;
  float* s1    = ws;               ws += (size_t)NH * NN;
  float* s2    = ws;               ws += (size_t)NH * NN;
  float* cat   = ws;               ws += (size_t)NN * NH * F1;
  float* Wh2   = ws;               ws += (size_t)NN * F1;
  float* s1b   = ws;               ws += NN;
  float* s2b   = ws;               ws += NN;
  float* t1    = ws;               ws += (size_t)NN * F2;
  float* t23   = ws;               ws += (size_t)NN * 2 * F3;
  float* z     = ws;               ws += (size_t)NN * F3;
  int*   colidx = (int*)ws;        ws += (size_t)NN * CAP;
  int*   deg    = (int*)ws;        ws += NN;
  float* part  = (float*)ws;       ws += (size_t)KS * NN * NH * F1;  // 32 MB

  k_front<<<512 + NN, 256, 0, stream>>>(x, W_heads, adj, part, colidx, deg);
  k_wh_comb<<<NN / 8, 256, 0, stream>>>(part, a_heads, Whcat, s1, s2);
  k_gat_heads<<<NN, 256, 0, stream>>>(colidx, deg, Whcat, s1, s2, cat);
  k_wh2<<<NN / 8, 256, 0, stream>>>(cat, W_att, a_att, Wh2, s1b, s2b);
  k_gat2t1<<<NN / 4, 256, 0, stream>>>(colidx, deg, Wh2, s1b, s2b, W1, t1);
  k_gcn1t23<<<NN / 4, 256, 0, stream>>>(colidx, deg, t1, W2, W3, t23);
  k_gcn2<<<NN / 4, 256, 0, stream>>>(colidx, deg, t23, eps, mu_out, lv_out, z);
  k_zzt<<<dim3(64, 64), 256, 0, stream>>>(z, adj_rec);
}

// Round 10
// 218.463 us; speedup vs baseline: 1.0806x; 1.0806x over previous
//
#include <hip/hip_runtime.h>
#include <math.h>

#define NN 4096
#define DD 512
#define F1 64
#define F2 32
#define F3 16
#define NH 4
#define ALPHA 0.2f
#define CAP 160   // max degree; Binomial(4096,0.01) mean 41, sigma 6.4 -> P(>160)~0
#define KS 8      // K-split factor for the big GEMM (512 blocks, K=64 each)

__device__ __forceinline__ float lrelu(float e) { return (e >= 0.f) ? e : ALPHA * e; }

// ---------------------------------------------------------------------------
// Kernel 0: build CSR from dense binary adj. One block per row, float4 scan.
// Kept SEPARATE from the gemm: round-9 measured the fused version at 56us
// (vs ~25us serial) — the gemm's 33KB LDS + 124 VGPR footprint capped csr
// block residency and starved its HBM streaming (1.3 TB/s vs ~6).
// ---------------------------------------------------------------------------
__global__ void k_csr(const float* __restrict__ adj, int* __restrict__ colidx,
                      int* __restrict__ deg) {
  __shared__ int cnt;
  int i = blockIdx.x, tid = threadIdx.x;
  if (tid == 0) cnt = 0;
  __syncthreads();
  const float4* arow = (const float4*)(adj + (size_t)i * NN);
  for (int t = tid; t < NN / 4; t += 256) {
    float4 v = arow[t];
    int base = t * 4;
    if (v.x != 0.f) { int p = atomicAdd(&cnt, 1); if (p < CAP) colidx[(size_t)i * CAP + p] = base; }
    if (v.y != 0.f) { int p = atomicAdd(&cnt, 1); if (p < CAP) colidx[(size_t)i * CAP + p] = base + 1; }
    if (v.z != 0.f) { int p = atomicAdd(&cnt, 1); if (p < CAP) colidx[(size_t)i * CAP + p] = base + 2; }
    if (v.w != 0.f) { int p = atomicAdd(&cnt, 1); if (p < CAP) colidx[(size_t)i * CAP + p] = base + 3; }
  }
  __syncthreads();
  if (tid == 0) deg[i] = cnt < CAP ? cnt : CAP;
}

// ---------------------------------------------------------------------------
// Kernel 1: Whcat partials = x @ Wcat, K-split SGEMM with 8x8 register tiles.
// NAMED float4 accumulators passed BY NAME into macros (no token pasting,
// no address-taken arrays -> register-resident; R8-verified at 219.6us).
// Tiling: grid (32,2,KS), 128x128 tile (2 heads), K=64/block in 2 chunks
// of 32, 8x8 per thread = 1 B LDS / FMA -> VALU/LDS co-bound.
// ---------------------------------------------------------------------------
#define FMA8(C0, C1, AV) { float av_ = (AV); \
  C0.x = fmaf(av_, bc0.x, C0.x); \
  C0.y = fmaf(av_, bc0.y, C0.y); \
  C0.z = fmaf(av_, bc0.z, C0.z); \
  C0.w = fmaf(av_, bc0.w, C0.w); \
  C1.x = fmaf(av_, bc1.x, C1.x); \
  C1.y = fmaf(av_, bc1.y, C1.y); \
  C1.z = fmaf(av_, bc1.z, C1.z); \
  C1.w = fmaf(av_, bc1.w, C1.w); }

#define STORE_ROW(C0, C1, ROWEXPR) { \
  int row_ = (ROWEXPR); \
  float* p_ = dst + (size_t)row_ * (NH * F1); \
  *(float4*)&p_[cg * 4] = C0; \
  *(float4*)&p_[cg * 4 + 64] = C1; }

__global__ __launch_bounds__(256) void k_wh_gemm(
    const float* __restrict__ x, const float* __restrict__ W_heads,
    float* __restrict__ part) {
  __shared__ float As[32][128];   // [kk][row] transposed, 16 KB
  __shared__ float Bs[32][128];   // [kk][col], 16 KB
  int tid = threadIdx.x;
  int nh = blockIdx.y;            // head pair: cols nh*128 .. nh*128+127
  int r0 = blockIdx.x * 128;
  int kb = blockIdx.z * 64;       // K range [kb, kb+64), 2 chunks of 32

  int arow = tid & 127, ahalf = tid >> 7;   // A staging: row, k-half(16)
  int bk = tid >> 5, bf = tid & 31;         // B staging: k-row base, col quad
  int rg = tid >> 4, cg = tid & 15;         // compute: rows rg*4(+64), cols cg*4(+64)

  const float* xa = x + (size_t)(r0 + arow) * DD + kb + ahalf * 16;
  int h = nh * 2 + (bf >> 4);
  const float* wsrc = W_heads + (size_t)h * DD * F1 + ((bf * 4) & 63);

  // prefetch chunk 0 into NAMED registers
  float4 pa0 = *(const float4*)(xa);
  float4 pa1 = *(const float4*)(xa + 4);
  float4 pa2 = *(const float4*)(xa + 8);
  float4 pa3 = *(const float4*)(xa + 12);
  float4 pb0 = *(const float4*)(wsrc + (size_t)(kb + bk) * F1);
  float4 pb1 = *(const float4*)(wsrc + (size_t)(kb + bk + 8) * F1);
  float4 pb2 = *(const float4*)(wsrc + (size_t)(kb + bk + 16) * F1);
  float4 pb3 = *(const float4*)(wsrc + (size_t)(kb + bk + 24) * F1);

  float4 c00 = {0,0,0,0}, c01 = {0,0,0,0};
  float4 c10 = {0,0,0,0}, c11 = {0,0,0,0};
  float4 c20 = {0,0,0,0}, c21 = {0,0,0,0};
  float4 c30 = {0,0,0,0}, c31 = {0,0,0,0};
  float4 c40 = {0,0,0,0}, c41 = {0,0,0,0};
  float4 c50 = {0,0,0,0}, c51 = {0,0,0,0};
  float4 c60 = {0,0,0,0}, c61 = {0,0,0,0};
  float4 c70 = {0,0,0,0}, c71 = {0,0,0,0};

#pragma unroll
  for (int c = 0; c < 2; ++c) {
    // store prefetched chunk into LDS (A transposed: scalar stores, 2-way max)
    {
      int kk0 = ahalf * 16;
      As[kk0 + 0][arow] = pa0.x; As[kk0 + 1][arow] = pa0.y;
      As[kk0 + 2][arow] = pa0.z; As[kk0 + 3][arow] = pa0.w;
      As[kk0 + 4][arow] = pa1.x; As[kk0 + 5][arow] = pa1.y;
      As[kk0 + 6][arow] = pa1.z; As[kk0 + 7][arow] = pa1.w;
      As[kk0 + 8][arow] = pa2.x; As[kk0 + 9][arow] = pa2.y;
      As[kk0 + 10][arow] = pa2.z; As[kk0 + 11][arow] = pa2.w;
      As[kk0 + 12][arow] = pa3.x; As[kk0 + 13][arow] = pa3.y;
      As[kk0 + 14][arow] = pa3.z; As[kk0 + 15][arow] = pa3.w;
      *(float4*)&Bs[bk][bf * 4] = pb0;
      *(float4*)&Bs[bk + 8][bf * 4] = pb1;
      *(float4*)&Bs[bk + 16][bf * 4] = pb2;
      *(float4*)&Bs[bk + 24][bf * 4] = pb3;
    }
    __syncthreads();
    if (c == 0) {   // issue chunk-1 loads; latency hides under chunk-0 FMAs
      pa0 = *(const float4*)(xa + 32);
      pa1 = *(const float4*)(xa + 36);
      pa2 = *(const float4*)(xa + 40);
      pa3 = *(const float4*)(xa + 44);
      pb0 = *(const float4*)(wsrc + (size_t)(kb + 32 + bk) * F1);
      pb1 = *(const float4*)(wsrc + (size_t)(kb + 32 + bk + 8) * F1);
      pb2 = *(const float4*)(wsrc + (size_t)(kb + 32 + bk + 16) * F1);
      pb3 = *(const float4*)(wsrc + (size_t)(kb + 32 + bk + 24) * F1);
    }
#pragma unroll
    for (int kk = 0; kk < 32; ++kk) {
      float4 ar0 = *(const float4*)&As[kk][rg * 4];
      float4 ar1 = *(const float4*)&As[kk][rg * 4 + 64];
      float4 bc0 = *(const float4*)&Bs[kk][cg * 4];
      float4 bc1 = *(const float4*)&Bs[kk][cg * 4 + 64];
      FMA8(c00, c01, ar0.x)
      FMA8(c10, c11, ar0.y)
      FMA8(c20, c21, ar0.z)
      FMA8(c30, c31, ar0.w)
      FMA8(c40, c41, ar1.x)
      FMA8(c50, c51, ar1.y)
      FMA8(c60, c61, ar1.z)
      FMA8(c70, c71, ar1.w)
    }
    if (c == 0) __syncthreads();
  }

  // write this K-slice's partial tile (Whcat layout: col = h*64+f)
  float* dst = part + (size_t)blockIdx.z * NN * (NH * F1) + nh * 128;
  STORE_ROW(c00, c01, r0 + rg * 4 + 0)
  STORE_ROW(c10, c11, r0 + rg * 4 + 1)
  STORE_ROW(c20, c21, r0 + rg * 4 + 2)
  STORE_ROW(c30, c31, r0 + rg * 4 + 3)
  STORE_ROW(c40, c41, r0 + 64 + rg * 4 + 0)
  STORE_ROW(c50, c51, r0 + 64 + rg * 4 + 1)
  STORE_ROW(c60, c61, r0 + 64 + rg * 4 + 2)
  STORE_ROW(c70, c71, r0 + 64 + rg * 4 + 3)
}

// ---------------------------------------------------------------------------
// Kernel 1b: combine KS partials -> Whcat (float4), fused s1/s2 reductions.
// Thread = (row-base tid>>6 in 0..3, quad tid&63 covering all 256 cols /
// 4 heads); each thread handles 2 rows -> full 8x256 coverage per block.
// ---------------------------------------------------------------------------
__global__ void k_wh_comb(const float* __restrict__ part,
                          const float* __restrict__ a_heads,
                          float* __restrict__ Whcat,
                          float* __restrict__ s1, float* __restrict__ s2) {
  int tid = threadIdx.x;
  int r0 = blockIdx.x * 8;
  int rb = tid >> 6;        // 0..3
  int c4 = tid & 63;        // quad col 0..63 (covers 256 cols)
  int h = c4 >> 4;          // 0..3: all 4 heads
  int f0 = (c4 & 15) * 4;
  float4 a1 = *(const float4*)&a_heads[h * 2 * F1 + f0];
  float4 a2 = *(const float4*)&a_heads[h * 2 * F1 + F1 + f0];
  const size_t stride = (size_t)NN * (NH * F1);
#pragma unroll
  for (int rr = 0; rr < 2; ++rr) {
    int row = r0 + rb * 2 + rr;
    size_t off = (size_t)row * (NH * F1) + c4 * 4;
    float4 v = *(const float4*)&part[off];
#pragma unroll
    for (int s = 1; s < KS; ++s) {
      float4 p = *(const float4*)&part[off + (size_t)s * stride];
      v.x += p.x; v.y += p.y; v.z += p.z; v.w += p.w;
    }
    *(float4*)&Whcat[off] = v;
    float v1 = v.x * a1.x + v.y * a1.y + v.z * a1.z + v.w * a1.w;
    float v2 = v.x * a2.x + v.y * a2.y + v.z * a2.z + v.w * a2.w;
#pragma unroll
    for (int o = 8; o > 0; o >>= 1) {
      v1 += __shfl_down(v1, o, 16);
      v2 += __shfl_down(v2, o, 16);
    }
    if ((tid & 15) == 0) {
      s1[h * NN + row] = v1;
      s2[h * NN + row] = v2;
    }
  }
}

// ---------------------------------------------------------------------------
// Kernel 2: multi-head GAT aggregation. Block per row; wave h = head h.
// ---------------------------------------------------------------------------
__global__ void k_gat_heads(const int* __restrict__ colidx, const int* __restrict__ deg,
                            const float* __restrict__ Whcat,
                            const float* __restrict__ s1, const float* __restrict__ s2,
                            float* __restrict__ cat) {
  __shared__ int idx[CAP];
  __shared__ float wsh[NH][CAP];
  int i = blockIdx.x, tid = threadIdx.x;
  int c = deg[i];
  for (int t = tid; t < c; t += 256) idx[t] = colidx[(size_t)i * CAP + t];
  __syncthreads();
  int h = tid >> 6;
  int f = tid & 63;
  const float* s2h = s2 + h * NN;
  float s1v = s1[h * NN + i];
  float M = -INFINITY;
  for (int k = f; k < c; k += 64) {
    float v = s2h[idx[k]];
    wsh[h][k] = v;
    M = fmaxf(M, v);
  }
#pragma unroll
  for (int off = 32; off > 0; off >>= 1) M = fmaxf(M, __shfl_down(M, off, 64));
  M = __shfl(M, 0, 64);
  float m = lrelu(s1v + M);
  float lsum = 0.f;
  for (int k = f; k < c; k += 64) {
    float w = __expf(lrelu(s1v + wsh[h][k]) - m);
    wsh[h][k] = w;
    lsum += w;
  }
#pragma unroll
  for (int off = 32; off > 0; off >>= 1) lsum += __shfl_down(lsum, off, 64);
  float linv = 1.f / __shfl(lsum, 0, 64);
  __syncthreads();
  const float* base = Whcat + h * 64 + f;
  float a0 = 0.f, a1 = 0.f, a2 = 0.f, a3 = 0.f;
  int k = 0;
  for (; k + 4 <= c; k += 4) {
    int j0 = idx[k], j1 = idx[k + 1], j2 = idx[k + 2], j3 = idx[k + 3];
    a0 = fmaf(wsh[h][k],     base[(size_t)j0 * 256], a0);
    a1 = fmaf(wsh[h][k + 1], base[(size_t)j1 * 256], a1);
    a2 = fmaf(wsh[h][k + 2], base[(size_t)j2 * 256], a2);
    a3 = fmaf(wsh[h][k + 3], base[(size_t)j3 * 256], a3);
  }
  for (; k < c; ++k) a0 = fmaf(wsh[h][k], base[(size_t)idx[k] * 256], a0);
  float o = (a0 + a1 + a2 + a3) * linv;
  cat[(size_t)i * (NH * F1) + tid] = (o > 0.f) ? o : expm1f(o);
}

// ---------------------------------------------------------------------------
// Kernel 3: Wh2 = cat @ W_att  [NN,256]x[256,64], plus s1b/s2b reductions
// ---------------------------------------------------------------------------
__global__ void k_wh2(const float* __restrict__ cat,
                      const float* __restrict__ W_att,
                      const float* __restrict__ a_att,
                      float* __restrict__ Wh2,
                      float* __restrict__ s1b, float* __restrict__ s2b) {
  const int ROWS = 8;
  __shared__ float cs[ROWS][NH * F1];
  int tid = threadIdx.x;
  int r0 = blockIdx.x * ROWS;
  const float4* csrc = (const float4*)(cat + (size_t)r0 * 256);
  for (int t = tid; t < ROWS * 256 / 4; t += 256) ((float4*)cs)[t] = csrc[t];
  __syncthreads();
  int g = tid >> 6;
  int f = tid & 63;
  float a1 = a_att[f], a2 = a_att[64 + f];
  const float* W = W_att + f;
#pragma unroll
  for (int rr = 0; rr < 2; ++rr) {
    int r = g * 2 + rr;
    float acc = 0.f;
    for (int k = 0; k < 256; k += 4) {
      float4 cv = *(const float4*)&cs[r][k];
      acc = fmaf(cv.x, W[(k + 0) * 64], acc);
      acc = fmaf(cv.y, W[(k + 1) * 64], acc);
      acc = fmaf(cv.z, W[(k + 2) * 64], acc);
      acc = fmaf(cv.w, W[(k + 3) * 64], acc);
    }
    Wh2[(size_t)(r0 + r) * 64 + f] = acc;
    float v1 = acc * a1, v2 = acc * a2;
#pragma unroll
    for (int off = 32; off > 0; off >>= 1) {
      v1 += __shfl_down(v1, off, 64);
      v2 += __shfl_down(v2, off, 64);
    }
    if (f == 0) { s1b[r0 + r] = v1; s2b[r0 + r] = v2; }
  }
}

// ---------------------------------------------------------------------------
// Kernel 4: single-head GAT + fused t1 = gc @ W1. 4 rows/block, wave per row.
// ---------------------------------------------------------------------------
__global__ void k_gat2t1(const int* __restrict__ colidx, const int* __restrict__ deg,
                         const float* __restrict__ Wh2,
                         const float* __restrict__ s1b, const float* __restrict__ s2b,
                         const float* __restrict__ W1, float* __restrict__ t1) {
  __shared__ int idx4[4][CAP];
  __shared__ float wsh4[4][CAP];
  __shared__ float grow[4][64];
  __shared__ float W1s[F1 * F2];  // 8 KB
  int tid = threadIdx.x;
  int w = tid >> 6, f = tid & 63;
  int i = blockIdx.x * 4 + w;
  int c = deg[i];
  for (int t = tid; t < F1 * F2; t += 256) W1s[t] = W1[t];
  for (int k = f; k < c; k += 64) idx4[w][k] = colidx[(size_t)i * CAP + k];
  __syncthreads();
  float s1v = s1b[i];
  float M = -INFINITY;
  for (int k = f; k < c; k += 64) {
    float v = s2b[idx4[w][k]];
    wsh4[w][k] = v;
    M = fmaxf(M, v);
  }
#pragma unroll
  for (int off = 32; off > 0; off >>= 1) M = fmaxf(M, __shfl_down(M, off, 64));
  M = __shfl(M, 0, 64);
  float m = lrelu(s1v + M);
  float lsum = 0.f;
  for (int k = f; k < c; k += 64) {
    float wv = __expf(lrelu(s1v + wsh4[w][k]) - m);
    wsh4[w][k] = wv;
    lsum += wv;
  }
#pragma unroll
  for (int off = 32; off > 0; off >>= 1) lsum += __shfl_down(lsum, off, 64);
  float linv = 1.f / __shfl(lsum, 0, 64);
  __syncthreads();
  const float* base = Wh2 + f;
  float a0 = 0.f, a1 = 0.f, a2 = 0.f, a3 = 0.f;
  int k = 0;
  for (; k + 4 <= c; k += 4) {
    int j0 = idx4[w][k], j1 = idx4[w][k + 1], j2 = idx4[w][k + 2], j3 = idx4[w][k + 3];
    a0 = fmaf(wsh4[w][k],     base[(size_t)j0 * 64], a0);
    a1 = fmaf(wsh4[w][k + 1], base[(size_t)j1 * 64], a1);
    a2 = fmaf(wsh4[w][k + 2], base[(size_t)j2 * 64], a2);
    a3 = fmaf(wsh4[w][k + 3], base[(size_t)j3 * 64], a3);
  }
  for (; k < c; ++k) a0 = fmaf(wsh4[w][k], base[(size_t)idx4[w][k] * 64], a0);
  float o = (a0 + a1 + a2 + a3) * linv;
  grow[w][f] = (o > 0.f) ? o : expm1f(o);
  __syncthreads();
  if (f < F2) {
    float acc = 0.f;
#pragma unroll 8
    for (int kk = 0; kk < F1; ++kk) acc = fmaf(grow[w][kk], W1s[kk * F2 + f], acc);
    t1[(size_t)i * F2 + f] = acc;
  }
}

// ---------------------------------------------------------------------------
// Kernel 5: h1 = relu(adj @ t1) fused with t23 = h1 @ [W2|W3].
// ---------------------------------------------------------------------------
__global__ void k_gcn1t23(const int* __restrict__ colidx, const int* __restrict__ deg,
                          const float* __restrict__ t1,
                          const float* __restrict__ W2, const float* __restrict__ W3,
                          float* __restrict__ t23) {
  __shared__ int idx4[4][CAP];
  __shared__ float hrow[4][F2];
  __shared__ float Wc[F2 * 32];  // [k][g]: g<16 -> W2, g>=16 -> W3
  int tid = threadIdx.x;
  int w = tid >> 6, lane = tid & 63;
  int nb = lane >> 5, g = lane & 31;
  int i = blockIdx.x * 4 + w;
  int c = deg[i];
  for (int t = tid; t < F2 * 32; t += 256) {
    int kk = t >> 5, gg = t & 31;
    Wc[t] = (gg < 16) ? W2[kk * 16 + gg] : W3[kk * 16 + (gg - 16)];
  }
  for (int k = lane; k < c; k += 64) idx4[w][k] = colidx[(size_t)i * CAP + k];
  __syncthreads();
  float a0 = 0.f, a1 = 0.f;
  int k = nb;
  for (; k + 2 < c; k += 4) {
    a0 += t1[(size_t)idx4[w][k] * F2 + g];
    a1 += t1[(size_t)idx4[w][k + 2] * F2 + g];
  }
  for (; k < c; k += 2) a0 += t1[(size_t)idx4[w][k] * F2 + g];
  float tot = a0 + a1;
  tot += __shfl_xor(tot, 32, 64);
  float h1v = fmaxf(tot, 0.f);
  if (nb == 0) hrow[w][g] = h1v;
  __syncthreads();
  if (lane < 32) {
    float acc = 0.f;
#pragma unroll 8
    for (int kk = 0; kk < F2; ++kk) acc = fmaf(hrow[w][kk], Wc[kk * 32 + lane], acc);
    t23[(size_t)i * 32 + lane] = acc;
  }
}

// ---------------------------------------------------------------------------
// Kernel 6: mu/logvar = adj @ t23 ; z = eps*exp(logvar)+mu. Wave per row.
// ---------------------------------------------------------------------------
__global__ void k_gcn2(const int* __restrict__ colidx, const int* __restrict__ deg,
                       const float* __restrict__ t23, const float* __restrict__ eps,
                       float* __restrict__ mu_out, float* __restrict__ lv_out,
                       float* __restrict__ z) {
  __shared__ int idx4[4][CAP];
  int tid = threadIdx.x;
  int w = tid >> 6, lane = tid & 63;
  int nb = lane >> 5, g = lane & 31;
  int i = blockIdx.x * 4 + w;
  int c = deg[i];
  for (int k = lane; k < c; k += 64) idx4[w][k] = colidx[(size_t)i * CAP + k];
  __syncthreads();
  float a0 = 0.f, a1 = 0.f;
  int k = nb;
  for (; k + 2 < c; k += 4) {
    a0 += t23[(size_t)idx4[w][k] * 32 + g];
    a1 += t23[(size_t)idx4[w][k + 2] * 32 + g];
  }
  for (; k < c; k += 2) a0 += t23[(size_t)idx4[w][k] * 32 + g];
  float tot = a0 + a1;
  tot += __shfl_xor(tot, 32, 64);
  float lvv = __shfl(tot, (lane & 31) + 16, 64);  // valid for g<16
  if (lane < 16) {
    mu_out[(size_t)i * 16 + g] = tot;
    z[(size_t)i * 16 + g] = eps[(size_t)i * 16 + g] * expf(lvv) + tot;
  } else if (lane < 32) {
    lv_out[(size_t)i * 16 + (g - 16)] = tot;
  }
}

// ---------------------------------------------------------------------------
// Kernel 7: adj_rec = z @ z^T. 64x64 tiles, rank-16, float4 stores.
// ---------------------------------------------------------------------------
__global__ void k_zzt(const float* __restrict__ z, float* __restrict__ out) {
  __shared__ float zr[64][17];
  __shared__ float zc[64][17];
  int bj = blockIdx.x, bi = blockIdx.y;
  int tid = threadIdx.x;
  for (int t = tid; t < 64 * 16; t += 256) {
    int r = t >> 4, kk = t & 15;
    zr[r][kk] = z[(size_t)(bi * 64 + r) * 16 + kk];
    zc[r][kk] = z[(size_t)(bj * 64 + r) * 16 + kk];
  }
  __syncthreads();
  int rg = tid >> 4;
  int cg = tid & 15;
  float acc[4][4] = {};
  for (int kk = 0; kk < 16; ++kk) {
    float av[4], bv[4];
#pragma unroll
    for (int t = 0; t < 4; ++t) av[t] = zr[rg * 4 + t][kk];
#pragma unroll
    for (int t = 0; t < 4; ++t) bv[t] = zc[cg * 4 + t][kk];
#pragma unroll
    for (int r = 0; r < 4; ++r)
#pragma unroll
      for (int cc = 0; cc < 4; ++cc) acc[r][cc] = fmaf(av[r], bv[cc], acc[r][cc]);
  }
#pragma unroll
  for (int r = 0; r < 4; ++r) {
    float4 v = make_float4(acc[r][0], acc[r][1], acc[r][2], acc[r][3]);
    *(float4*)&out[(size_t)(bi * 64 + rg * 4 + r) * NN + bj * 64 + cg * 4] = v;
  }
}

extern "C" void kernel_launch(void* const* d_in, const int* in_sizes, int n_in,
                              void* d_out, int out_size, void* d_ws, size_t ws_size,
                              hipStream_t stream) {
  const float* x       = (const float*)d_in[0];
  const float* adj     = (const float*)d_in[1];
  const float* W_heads = (const float*)d_in[2];
  const float* a_heads = (const float*)d_in[3];
  const float* W_att   = (const float*)d_in[4];
  const float* a_att   = (const float*)d_in[5];
  const float* W1      = (const float*)d_in[6];
  const float* W2      = (const float*)d_in[7];
  const float* W3      = (const float*)d_in[8];
  const float* eps     = (const float*)d_in[9];

  float* out = (float*)d_out;
  float* adj_rec = out;
  float* mu_out  = out + (size_t)NN * NN;
  float* lv_out  = mu_out + (size_t)NN * F3;

  float* ws = (float*)d_ws;
  float* Whcat = ws;               ws += (size_t)NN * NH * F1;
  float* s1    = ws;               ws += (size_t)NH * NN;
  float* s2    = ws;               ws += (size_t)NH * NN;
  float* cat   = ws;               ws += (size_t)NN * NH * F1;
  float* Wh2   = ws;               ws += (size_t)NN * F1;
  float* s1b   = ws;               ws += NN;
  float* s2b   = ws;               ws += NN;
  float* t1    = ws;               ws += (size_t)NN * F2;
  float* t23   = ws;               ws += (size_t)NN * 2 * F3;
  float* z     = ws;               ws += (size_t)NN * F3;
  int*   colidx = (int*)ws;        ws += (size_t)NN * CAP;
  int*   deg    = (int*)ws;        ws += NN;
  float* part  = (float*)ws;       ws += (size_t)KS * NN * NH * F1;  // 32 MB

  k_csr<<<NN, 256, 0, stream>>>(adj, colidx, deg);
  k_wh_gemm<<<dim3(32, 2, KS), 256, 0, stream>>>(x, W_heads, part);
  k_wh_comb<<<NN / 8, 256, 0, stream>>>(part, a_heads, Whcat, s1, s2);
  k_gat_heads<<<NN, 256, 0, stream>>>(colidx, deg, Whcat, s1, s2, cat);
  k_wh2<<<NN / 8, 256, 0, stream>>>(cat, W_att, a_att, Wh2, s1b, s2b);
  k_gat2t1<<<NN / 4, 256, 0, stream>>>(colidx, deg, Wh2, s1b, s2b, W1, t1);
  k_gcn1t23<<<NN / 4, 256, 0, stream>>>(colidx, deg, t1, W2, W3, t23);
  k_gcn2<<<NN / 4, 256, 0, stream>>>(colidx, deg, t23, eps, mu_out, lv_out, z);
  k_zzt<<<dim3(64, 64), 256, 0, stream>>>(z, adj_rec);
}